// Round 2
// baseline (489.788 us; speedup 1.0000x reference)
//
#include <hip/hip_runtime.h>

// HyperConnections: b=4, S=4, I=1, L=2048, D=2048. ALL tensors float32.
//
// Algebra: out[s,d] = sum_{s'} ( alpha[s'][s+1] + beta[s]*alpha[s'][0] ) * x[s',d]
//   alpha[s][t] = tanh( rms_s * sum_d x[s,d]*w[d]*A[d,t] ) * a_scale + static_alpha[s,t]
//   beta[s]     = tanh( rms_s * sum_d x[s,d]*w[d]*Bfn[d] ) * b_scale + static_beta[s]
//   rms_s = rsqrt(mean_d(x^2) + f32_eps); w folds into projections (prep_kernel).
//
// V2 structure (resubmit — round 1 failure was container infra, not the kernel):
// waves own d-chunks (256 floats), NOT rows. Each lane holds one float4 of each
// of the 4 rows in registers across the single barrier; the 4x4 mix is done
// in-register (no 32KB LDS staging, no LDS round-trip). WA/WB are read once per
// block (was 4x). LDS = 8 waves x 28 partial sums = 896 B.

#define DD 2048
#define NS 4
#define NT 5
#define NW 8                      // waves per block (512 threads)
#define ROWSTRIDE ((size_t)DD * 2048)

typedef float v4f __attribute__((ext_vector_type(4)));

// Fold norm_weight into alpha/beta projections, transposed for coalesced reads.
__global__ void prep_kernel(const float* __restrict__ w,
                            const float* __restrict__ A,    // (D, 5) row-major
                            const float* __restrict__ Bfn,  // (D, 1)
                            float* __restrict__ WA,         // (5, D)
                            float* __restrict__ WB) {       // (D)
    int d = blockIdx.x * blockDim.x + threadIdx.x;
    if (d >= DD) return;
    float wf = w[d];
#pragma unroll
    for (int t = 0; t < NT; ++t)
        WA[t * DD + d] = wf * A[d * NT + t];
    WB[d] = wf * Bfn[d];
}

__device__ __forceinline__ float dot4(v4f a, v4f b) {
    return fmaf(a.x, b.x, fmaf(a.y, b.y, fmaf(a.z, b.z, a.w * b.w)));
}

__global__ __launch_bounds__(512, 6) void hyper_kernel(
    const float* __restrict__ X,    // residuals (16, 2048, 2048)
    const float* __restrict__ WA,   // (5, D)  w folded in
    const float* __restrict__ WB,   // (D)     w folded in
    const float* __restrict__ sA,   // static_alpha (4,5)
    const float* __restrict__ sB,   // static_beta  (4,1)
    const float* __restrict__ aS,   // dynamic_alpha_scale (1)
    const float* __restrict__ bS,   // dynamic_beta_scale  (1)
    float* __restrict__ out)
{
    __shared__ float shP[NW][NS][7];   // per-wave partials: a[0..4], ab, ss

    const int g  = blockIdx.x;               // group = (bb, l)
    const int bb = g >> 11;
    const int l  = g & 2047;
    const int wv = threadIdx.x >> 6;         // wave = d-chunk index (8 x 256)
    const int ln = threadIdx.x & 63;
    const int d0 = (wv << 8) + (ln << 2);    // this lane's float4 position

    const size_t base = ((size_t)(bb * NS) * 2048 + (size_t)l) * (size_t)DD + (size_t)d0;

    // ---- Load: one float4 per row, kept in registers for the whole kernel.
    v4f xv[NS];
#pragma unroll
    for (int s = 0; s < NS; ++s)
        xv[s] = *(const v4f*)(X + base + (size_t)s * ROWSTRIDE);

    // Projection vectors for this lane's d-chunk (each WA elem read ONCE per block).
    v4f wt[6];
#pragma unroll
    for (int t = 0; t < NT; ++t)
        wt[t] = *(const v4f*)(WA + t * DD + d0);
    wt[5] = *(const v4f*)(WB + d0);

    // ---- Per-lane partial dots: 4 rows x {5 alpha, 1 beta, 1 sumsq}
    float acc[NS][7];
#pragma unroll
    for (int s = 0; s < NS; ++s) {
#pragma unroll
        for (int t = 0; t < 6; ++t)
            acc[s][t] = dot4(xv[s], wt[t]);
        acc[s][6] = dot4(xv[s], xv[s]);
    }

    // ---- Wave butterfly reduction (sums complete in every lane; lane 0 writes)
#pragma unroll
    for (int m = 1; m < 64; m <<= 1) {
#pragma unroll
        for (int s = 0; s < NS; ++s)
#pragma unroll
            for (int k = 0; k < 7; ++k)
                acc[s][k] += __shfl_xor(acc[s][k], m);
    }

    if (ln == 0) {
#pragma unroll
        for (int s = 0; s < NS; ++s)
#pragma unroll
            for (int k = 0; k < 7; ++k)
                shP[wv][s][k] = acc[s][k];
    }
    __syncthreads();   // the ONLY barrier

    // ---- Coefficients: one tanh per lane (24 lanes), broadcast via shfl.
    // lane i<20: alpha[s=i/5][t=i%5]; lane 20+s: beta[s].
    const float ascale = aS[0];
    const float bscale = bS[0];
    float val = 0.f;
    if (ln < 24) {
        const bool isA = ln < 20;
        const int s   = isA ? (ln / 5) : (ln - 20);
        const int idx = isA ? (ln % 5) : 5;
        float dv = 0.f, sv = 0.f;
#pragma unroll
        for (int w = 0; w < NW; ++w) {
            dv += shP[w][s][idx];
            sv += shP[w][s][6];
        }
        const float rms = rsqrtf(sv * (1.0f / 2048.0f) + 1.1920929e-07f); // f32 eps
        const float th  = tanhf(rms * dv);
        val = isA ? fmaf(th, ascale, sA[ln]) : fmaf(th, bscale, sB[s]);
    }

    float bet[NS];
#pragma unroll
    for (int s = 0; s < NS; ++s) bet[s] = __shfl(val, 20 + s);

    // c[s][s'] = alpha[s'][s+1] + beta[s] * alpha[s'][0]
    float c[NS][NS];
#pragma unroll
    for (int sp = 0; sp < NS; ++sp) {
        const float a0 = __shfl(val, sp * 5);
#pragma unroll
        for (int s = 0; s < NS; ++s)
            c[s][sp] = fmaf(bet[s], a0, __shfl(val, sp * 5 + s + 1));
    }

    // ---- In-register 4x4 row mix; nontemporal stores keep X resident in L3.
#pragma unroll
    for (int s = 0; s < NS; ++s) {
        v4f o = c[s][0] * xv[0] + c[s][1] * xv[1] + c[s][2] * xv[2] + c[s][3] * xv[3];
        __builtin_nontemporal_store(o, (v4f*)(out + base + (size_t)s * ROWSTRIDE));
    }
}

extern "C" void kernel_launch(void* const* d_in, const int* in_sizes, int n_in,
                              void* d_out, int out_size, void* d_ws, size_t ws_size,
                              hipStream_t stream) {
    const float* X   = (const float*)d_in[0]; // residuals (16,2048,2048)
    const float* w   = (const float*)d_in[1]; // norm_weight (2048)
    const float* sA  = (const float*)d_in[2]; // static_alpha (4,5)
    const float* sB  = (const float*)d_in[3]; // static_beta (4,1)
    const float* Afn = (const float*)d_in[4]; // dynamic_alpha_fn (2048,5)
    const float* aSc = (const float*)d_in[5]; // dynamic_alpha_scale (1)
    const float* Bfn = (const float*)d_in[6]; // dynamic_beta_fn (2048,1)
    const float* bSc = (const float*)d_in[7]; // dynamic_beta_scale (1)
    float* out = (float*)d_out;

    float* WA = (float*)d_ws;      // 5*2048 f32 = 40 KiB
    float* WB = WA + 5 * 2048;     // 2048 f32   =  8 KiB

    prep_kernel<<<8, 256, 0, stream>>>(w, Afn, Bfn, WA, WB);
    hyper_kernel<<<4 * 2048, 512, 0, stream>>>(X, WA, WB, sA, sB, aSc, bSc, out);
}

// Round 3
// 460.661 us; speedup vs baseline: 1.0632x; 1.0632x over previous
//
#include <hip/hip_runtime.h>

// HyperConnections: b=4, S=4, I=1, L=2048, D=2048. ALL tensors float32.
//
// Algebra: out[s,d] = sum_{s'} ( alpha[s'][s+1] + beta[s]*alpha[s'][0] ) * x[s',d]
//   alpha[s][t] = tanh( rms_s * sum_d x[s,d]*w[d]*A[d,t] ) * a_scale + static_alpha[s,t]
//   beta[s]     = tanh( rms_s * sum_d x[s,d]*w[d]*Bfn[d] ) * b_scale + static_beta[s]
//   rms_s = rsqrt(mean_d(x^2) + f32_eps); w folds into projections (prep_kernel).
//
// V3: V2's register-resident d-chunk layout (X read once, mix in-register), but
// the 28-value in-wave shfl butterfly (168 ds_bpermute + 168 dependent adds) is
// replaced by an LDS-transpose reduction: each lane dumps 7 float4 partials
// (conflict-free ds_write_b128); waves 0..6 then each reduce one 2KB chunk.
// Normal stores (nt caused +18% WRITE_SIZE). launch_bounds(512,4) gives the
// compiler 128 VGPRs so all 10 up-front loads stay in flight (V2's 40-VGPR
// allocation serialized them -> MLP-bound at 2.4 TB/s).

#define DD 2048
#define NS 4
#define NT 5
#define NW 8                      // waves per block (512 threads)
#define ROWSTRIDE ((size_t)DD * 2048)

typedef float v4f __attribute__((ext_vector_type(4)));

// Fold norm_weight into alpha/beta projections, transposed for coalesced reads.
__global__ void prep_kernel(const float* __restrict__ w,
                            const float* __restrict__ A,    // (D, 5) row-major
                            const float* __restrict__ Bfn,  // (D, 1)
                            float* __restrict__ WA,         // (5, D)
                            float* __restrict__ WB) {       // (D)
    int d = blockIdx.x * blockDim.x + threadIdx.x;
    if (d >= DD) return;
    float wf = w[d];
#pragma unroll
    for (int t = 0; t < NT; ++t)
        WA[t * DD + d] = wf * A[d * NT + t];
    WB[d] = wf * Bfn[d];
}

__device__ __forceinline__ float dot4(v4f a, v4f b) {
    return fmaf(a.x, b.x, fmaf(a.y, b.y, fmaf(a.z, b.z, a.w * b.w)));
}

__global__ __launch_bounds__(512, 4) void hyper_kernel(
    const float* __restrict__ X,    // residuals (16, 2048, 2048)
    const float* __restrict__ WA,   // (5, D)  w folded in
    const float* __restrict__ WB,   // (D)     w folded in
    const float* __restrict__ sA,   // static_alpha (4,5)
    const float* __restrict__ sB,   // static_beta  (4,1)
    const float* __restrict__ aS,   // dynamic_alpha_scale (1)
    const float* __restrict__ bS,   // dynamic_beta_scale  (1)
    float* __restrict__ out)
{
    // part[c][w][ln]: raw per-lane partials, chunk c = accumulators 4c..4c+3.
    // Writes/reads are lane-consecutive float4 -> conflict-free. 57,344 B.
    __shared__ __align__(16) v4f  part[7][NW][64];
    __shared__ __align__(16) float shS[28];   // block-level sums, k = s*7+t

    const int g  = blockIdx.x;               // group = (bb, l)
    const int bb = g >> 11;
    const int l  = g & 2047;
    const int wv = threadIdx.x >> 6;         // wave = d-chunk index (8 x 256)
    const int ln = threadIdx.x & 63;
    const int d0 = (wv << 8) + (ln << 2);    // this lane's float4 position

    const size_t base = ((size_t)(bb * NS) * 2048 + (size_t)l) * (size_t)DD + (size_t)d0;

    // ---- Load: one float4 per row, kept in registers for the whole kernel.
    v4f xv[NS];
#pragma unroll
    for (int s = 0; s < NS; ++s)
        xv[s] = *(const v4f*)(X + base + (size_t)s * ROWSTRIDE);

    // Projection vectors for this lane's d-chunk (each WA elem read ONCE per block).
    v4f wt[6];
#pragma unroll
    for (int t = 0; t < NT; ++t)
        wt[t] = *(const v4f*)(WA + t * DD + d0);
    wt[5] = *(const v4f*)(WB + d0);

    // ---- Per-lane partial dots: k = s*7 + t; t=5 is beta-dot, t=6 is sumsq.
    float acc[28];
#pragma unroll
    for (int s = 0; s < NS; ++s) {
#pragma unroll
        for (int t = 0; t < 6; ++t)
            acc[s * 7 + t] = dot4(xv[s], wt[t]);
        acc[s * 7 + 6] = dot4(xv[s], xv[s]);
    }

    // ---- Dump raw partials to LDS (7 conflict-free ds_write_b128 per lane).
#pragma unroll
    for (int c = 0; c < 7; ++c) {
        v4f p;
        p.x = acc[4 * c + 0]; p.y = acc[4 * c + 1];
        p.z = acc[4 * c + 2]; p.w = acc[4 * c + 3];
        part[c][wv][ln] = p;
    }
    __syncthreads();

    // ---- Waves 0..6: reduce chunk c=wv (512 float4 -> 1 float4).
    if (wv < 7) {
        v4f t4 = part[wv][0][ln];
#pragma unroll
        for (int j = 1; j < NW; ++j)
            t4 += part[wv][j][ln];
#pragma unroll
        for (int m = 1; m < 64; m <<= 1) {
            t4.x += __shfl_xor(t4.x, m);
            t4.y += __shfl_xor(t4.y, m);
            t4.z += __shfl_xor(t4.z, m);
            t4.w += __shfl_xor(t4.w, m);
        }
        if (ln == 0)
            *(v4f*)&shS[4 * wv] = t4;
    }
    __syncthreads();

    // ---- Coefficients: one tanh per lane (24 lanes), broadcast via shfl.
    // lane i<20: alpha[s=i/5][t=i%5]; lane 20+s: beta[s].
    const float ascale = aS[0];
    const float bscale = bS[0];
    float val = 0.f;
    if (ln < 24) {
        const bool isA = ln < 20;
        const int s   = isA ? (ln / 5) : (ln - 20);
        const int idx = isA ? (ln % 5) : 5;
        const float dv = shS[s * 7 + idx];
        const float sv = shS[s * 7 + 6];
        const float rms = rsqrtf(sv * (1.0f / 2048.0f) + 1.1920929e-07f); // f32 eps
        const float th  = tanhf(rms * dv);
        val = isA ? fmaf(th, ascale, sA[ln]) : fmaf(th, bscale, sB[s]);
    }

    float bet[NS];
#pragma unroll
    for (int s = 0; s < NS; ++s) bet[s] = __shfl(val, 20 + s);

    // c[s][s'] = alpha[s'][s+1] + beta[s] * alpha[s'][0]
    float c[NS][NS];
#pragma unroll
    for (int sp = 0; sp < NS; ++sp) {
        const float a0 = __shfl(val, sp * 5);
#pragma unroll
        for (int s = 0; s < NS; ++s)
            c[s][sp] = fmaf(bet[s], a0, __shfl(val, sp * 5 + s + 1));
    }

    // ---- In-register 4x4 row mix; plain stores (nt caused write amplification).
#pragma unroll
    for (int s = 0; s < NS; ++s) {
        v4f o = c[s][0] * xv[0] + c[s][1] * xv[1] + c[s][2] * xv[2] + c[s][3] * xv[3];
        *(v4f*)(out + base + (size_t)s * ROWSTRIDE) = o;
    }
}

extern "C" void kernel_launch(void* const* d_in, const int* in_sizes, int n_in,
                              void* d_out, int out_size, void* d_ws, size_t ws_size,
                              hipStream_t stream) {
    const float* X   = (const float*)d_in[0]; // residuals (16,2048,2048)
    const float* w   = (const float*)d_in[1]; // norm_weight (2048)
    const float* sA  = (const float*)d_in[2]; // static_alpha (4,5)
    const float* sB  = (const float*)d_in[3]; // static_beta (4,1)
    const float* Afn = (const float*)d_in[4]; // dynamic_alpha_fn (2048,5)
    const float* aSc = (const float*)d_in[5]; // dynamic_alpha_scale (1)
    const float* Bfn = (const float*)d_in[6]; // dynamic_beta_fn (2048,1)
    const float* bSc = (const float*)d_in[7]; // dynamic_beta_scale (1)
    float* out = (float*)d_out;

    float* WA = (float*)d_ws;      // 5*2048 f32 = 40 KiB
    float* WB = WA + 5 * 2048;     // 2048 f32   =  8 KiB

    prep_kernel<<<8, 256, 0, stream>>>(w, Afn, Bfn, WA, WB);
    hyper_kernel<<<4 * 2048, 512, 0, stream>>>(X, WA, WB, sA, sB, aSc, bSc, out);
}